// Round 1
// baseline (568.217 us; speedup 1.0000x reference)
//
#include <hip/hip_runtime.h>
#include <hip/hip_bf16.h>
#include <math.h>

#define N_Q     16384
#define DDIM    512
#define M_SLOTS 2048
#define EPSN    1e-12f
#define TEMPU   1e-5f

// ---------- helpers ----------
__device__ __forceinline__ unsigned int mapf(float f) {
    // monotone map float -> uint (preserves order for atomicMax)
    unsigned int b = __float_as_uint(f);
    return (b & 0x80000000u) ? ~b : (b | 0x80000000u);
}
__device__ __forceinline__ float unmapf(unsigned int u) {
    unsigned int b = (u & 0x80000000u) ? (u ^ 0x80000000u) : ~u;
    return __uint_as_float(b);
}
__device__ __forceinline__ float bf2f(unsigned short u) {
    return __uint_as_float(((unsigned int)u) << 16);
}
__device__ __forceinline__ unsigned short f2bf(float f) {
    unsigned int b = __float_as_uint(f);
    unsigned int r = (b + 0x7FFFu + ((b >> 16) & 1u)) >> 16;  // RNE
    return (unsigned short)r;
}

// reduce-sum across 128 threads (2 waves)
__device__ __forceinline__ float block_reduce_sum_128(float v, float* sred, int t) {
    #pragma unroll
    for (int o = 32; o > 0; o >>= 1) v += __shfl_down(v, o, 64);
    if ((t & 63) == 0) sred[t >> 6] = v;
    __syncthreads();
    return sred[0] + sred[1];
}

// ---------- kernel 1: L2-normalize query rows, store bf16 ----------
__global__ __launch_bounds__(128) void k_normalize(const float* __restrict__ q,
                                                   unsigned short* __restrict__ qbf) {
    __shared__ float sred[2];
    int row = blockIdx.x;
    int t = threadIdx.x;  // 128 threads, 4 floats each
    const float* rp = q + (size_t)row * DDIM;
    float4 v = ((const float4*)rp)[t];
    float ss = v.x * v.x + v.y * v.y + v.z * v.z + v.w * v.w;
    ss = block_reduce_sum_128(ss, sred, t);
    float inv = 1.0f / fmaxf(sqrtf(ss), EPSN);
    ushort4 o4;
    o4.x = f2bf(v.x * inv);
    o4.y = f2bf(v.y * inv);
    o4.z = f2bf(v.z * inv);
    o4.w = f2bf(v.w * inv);
    ((ushort4*)(qbf + (size_t)row * DDIM))[t] = o4;
}

// ---------- kernel 2: score GEMM + fused row-argmax / col-max ----------
#define BM 64
#define BN 64
#define BK 16

__global__ __launch_bounds__(256) void k_score(const unsigned short* __restrict__ qbf,
                                               const float* __restrict__ keys,
                                               unsigned long long* __restrict__ rowpack,
                                               unsigned int* __restrict__ colmax) {
    __shared__ float As[BK][BM];      // As[k][m]
    __shared__ float Bs[BK][BN];      // Bs[k][n]  (keys^T tile)
    __shared__ float colred[16][BN];

    int tid = threadIdx.x;
    int tx = tid & 15;        // col group
    int ty = tid >> 4;        // row group
    int n0 = blockIdx.y * BM;
    int j0 = blockIdx.x * BN;

    float acc[4][4] = {};

    int arow = tid >> 2, aq = tid & 3;   // A stage: 64 rows x 16 cols (ushort)
    int brow = tid >> 2, bq = tid & 3;   // B stage: 64 rows x 16 cols (float)

    for (int k0 = 0; k0 < DDIM; k0 += BK) {
        __syncthreads();
        // stage A (bf16 -> f32)
        {
            ushort4 a4 = *(const ushort4*)(qbf + (size_t)(n0 + arow) * DDIM + k0 + aq * 4);
            As[aq * 4 + 0][arow] = bf2f(a4.x);
            As[aq * 4 + 1][arow] = bf2f(a4.y);
            As[aq * 4 + 2][arow] = bf2f(a4.z);
            As[aq * 4 + 3][arow] = bf2f(a4.w);
        }
        // stage B (keys tile, transposed into Bs[k][n])
        {
            float4 b4 = *(const float4*)(keys + (size_t)(j0 + brow) * DDIM + k0 + bq * 4);
            Bs[bq * 4 + 0][brow] = b4.x;
            Bs[bq * 4 + 1][brow] = b4.y;
            Bs[bq * 4 + 2][brow] = b4.z;
            Bs[bq * 4 + 3][brow] = b4.w;
        }
        __syncthreads();
        #pragma unroll
        for (int kk = 0; kk < BK; ++kk) {
            float4 a = *(const float4*)&As[kk][ty * 4];
            float4 b = *(const float4*)&Bs[kk][tx * 4];
            float av[4] = {a.x, a.y, a.z, a.w};
            float bv[4] = {b.x, b.y, b.z, b.w};
            #pragma unroll
            for (int i = 0; i < 4; ++i)
                #pragma unroll
                for (int j = 0; j < 4; ++j)
                    acc[i][j] = fmaf(av[i], bv[j], acc[i][j]);
        }
    }

    // ---- fused epilogue ----
    // row argmax over this block's 64 columns (shfl across the 16 tx lanes)
    #pragma unroll
    for (int i = 0; i < 4; ++i) {
        float val = acc[i][0];
        int col = j0 + tx * 4;
        #pragma unroll
        for (int j = 1; j < 4; ++j) {
            if (acc[i][j] > val) { val = acc[i][j]; col = j0 + tx * 4 + j; }
        }
        #pragma unroll
        for (int off = 1; off < 16; off <<= 1) {
            float ov = __shfl_xor(val, off, 64);
            int oc = __shfl_xor(col, off, 64);
            if (ov > val || (ov == val && oc < col)) { val = ov; col = oc; }
        }
        if (tx == 0) {
            unsigned long long pk =
                ((unsigned long long)mapf(val) << 32) |
                (unsigned long long)(~(unsigned int)col);   // ~col: ties -> smaller col wins
            atomicMax(rowpack + (n0 + ty * 4 + i), pk);
        }
    }
    // col max over this block's 64 rows
    #pragma unroll
    for (int j = 0; j < 4; ++j) {
        float cmv = fmaxf(fmaxf(acc[0][j], acc[1][j]), fmaxf(acc[2][j], acc[3][j]));
        colred[ty][tx * 4 + j] = cmv;
    }
    __syncthreads();
    if (tid < 64) {
        float m = colred[0][tid];
        #pragma unroll
        for (int r = 1; r < 16; ++r) m = fmaxf(m, colred[r][tid]);
        atomicMax(colmax + j0 + tid, mapf(m));
    }
}

// ---------- kernel 3: weights + scatter-add ----------
__global__ __launch_bounds__(128) void k_scatter(const unsigned short* __restrict__ qbf,
                                                 const unsigned long long* __restrict__ rowpack,
                                                 const unsigned int* __restrict__ colmax,
                                                 float* __restrict__ upd) {
    int n = blockIdx.x;
    unsigned long long p = rowpack[n];
    float val = unmapf((unsigned int)(p >> 32));
    int g = (int)(~(unsigned int)(p & 0xFFFFFFFFull));
    float cm = unmapf(colmax[g]);
    float w = expf(val - cm);   // <= 1 always
    int t = threadIdx.x;        // 128 threads, 4 elems each
    ushort4 u4 = ((const ushort4*)(qbf + (size_t)n * DDIM))[t];
    float* dst = upd + (size_t)g * DDIM + t * 4;
    atomicAdd(dst + 0, w * bf2f(u4.x));
    atomicAdd(dst + 1, w * bf2f(u4.y));
    atomicAdd(dst + 2, w * bf2f(u4.z));
    atomicAdd(dst + 3, w * bf2f(u4.w));
}

// ---------- kernel 4: final normalize ----------
__global__ __launch_bounds__(128) void k_final(const float* __restrict__ keys,
                                               const float* __restrict__ upd,
                                               float* __restrict__ out) {
    __shared__ float sred[2];
    int j = blockIdx.x;
    int t = threadIdx.x;
    float4 k4 = ((const float4*)(keys + (size_t)j * DDIM))[t];
    float4 u4 = ((const float4*)(upd + (size_t)j * DDIM))[t];
    float4 v;
    v.x = fmaf(TEMPU, u4.x, k4.x);
    v.y = fmaf(TEMPU, u4.y, k4.y);
    v.z = fmaf(TEMPU, u4.z, k4.z);
    v.w = fmaf(TEMPU, u4.w, k4.w);
    float ss = v.x * v.x + v.y * v.y + v.z * v.z + v.w * v.w;
    ss = block_reduce_sum_128(ss, sred, t);
    float inv = 1.0f / fmaxf(sqrtf(ss), EPSN);
    v.x *= inv; v.y *= inv; v.z *= inv; v.w *= inv;
    ((float4*)(out + (size_t)j * DDIM))[t] = v;
}

// ---------- launch ----------
extern "C" void kernel_launch(void* const* d_in, const int* in_sizes, int n_in,
                              void* d_out, int out_size, void* d_ws, size_t ws_size,
                              hipStream_t stream) {
    const float* query = (const float*)d_in[0];   // [16384, 512] f32
    const float* keys  = (const float*)d_in[1];   // [2048, 512] f32
    float* out = (float*)d_out;                   // [2048, 512] f32

    char* ws = (char*)d_ws;
    const size_t OFF_QBF  = 0;                    // 16384*512*2   = 16,777,216 B
    const size_t OFF_ROW  = 16777216;             // 16384*8       =    131,072 B
    const size_t OFF_CMAX = OFF_ROW + 131072;     // 2048*4        =      8,192 B
    const size_t OFF_UPD  = OFF_CMAX + 8192;      // 2048*512*4    =  4,194,304 B

    unsigned short*     qbf     = (unsigned short*)(ws + OFF_QBF);
    unsigned long long* rowpack = (unsigned long long*)(ws + OFF_ROW);
    unsigned int*       cmax    = (unsigned int*)(ws + OFF_CMAX);
    float*              upd     = (float*)(ws + OFF_UPD);

    // zero rowpack + colmax + upd (0 == "-inf" under mapf packing)
    hipMemsetAsync(ws + OFF_ROW, 0, 131072 + 8192 + 2048 * 512 * 4, stream);

    k_normalize<<<N_Q, 128, 0, stream>>>(query, qbf);

    dim3 g2(M_SLOTS / BN, N_Q / BM);  // 32 x 256
    k_score<<<g2, 256, 0, stream>>>(qbf, keys, rowpack, cmax);

    k_scatter<<<N_Q, 128, 0, stream>>>(qbf, rowpack, cmax, upd);

    k_final<<<M_SLOTS, 128, 0, stream>>>(keys, upd, out);
}

// Round 2
// 200.315 us; speedup vs baseline: 2.8366x; 2.8366x over previous
//
#include <hip/hip_runtime.h>
#include <hip/hip_bf16.h>
#include <math.h>

#define N_Q     16384
#define DDIM    512
#define M_SLOTS 2048
#define EPSN    1e-12f
#define TEMPU   1e-5f

typedef unsigned int u32;
typedef unsigned long long u64;
typedef __attribute__((ext_vector_type(8))) short bf16x8;
typedef __attribute__((ext_vector_type(4))) float f32x4;

// ---------- helpers ----------
__device__ __forceinline__ u32 mapf(float f) {
    u32 b = __float_as_uint(f);
    return (b & 0x80000000u) ? ~b : (b | 0x80000000u);
}
__device__ __forceinline__ float unmapf(u32 u) {
    u32 b = (u & 0x80000000u) ? (u ^ 0x80000000u) : ~u;
    return __uint_as_float(b);
}
__device__ __forceinline__ float bf2f(unsigned short u) {
    return __uint_as_float(((u32)u) << 16);
}
__device__ __forceinline__ unsigned short f2bf(float f) {
    u32 b = __float_as_uint(f);
    u32 r = (b + 0x7FFFu + ((b >> 16) & 1u)) >> 16;  // RNE
    return (unsigned short)r;
}
__device__ __forceinline__ void gld_lds16(const unsigned short* g, unsigned short* l) {
    __builtin_amdgcn_global_load_lds(
        (const __attribute__((address_space(1))) u32*)(g),
        (__attribute__((address_space(3))) u32*)(l), 16, 0, 0);
}
__device__ __forceinline__ float block_reduce_sum_128(float v, float* sred, int t) {
    #pragma unroll
    for (int o = 32; o > 0; o >>= 1) v += __shfl_down(v, o, 64);
    if ((t & 63) == 0) sred[t >> 6] = v;
    __syncthreads();
    return sred[0] + sred[1];
}

// ---------- kernel 1: L2-normalize query rows, store bf16 ----------
__global__ __launch_bounds__(128) void k_normalize(const float* __restrict__ q,
                                                   unsigned short* __restrict__ qbf) {
    __shared__ float sred[2];
    int row = blockIdx.x;
    int t = threadIdx.x;
    const float* rp = q + (size_t)row * DDIM;
    float4 v = ((const float4*)rp)[t];
    float ss = v.x * v.x + v.y * v.y + v.z * v.z + v.w * v.w;
    ss = block_reduce_sum_128(ss, sred, t);
    float inv = 1.0f / fmaxf(sqrtf(ss), EPSN);
    ushort4 o4;
    o4.x = f2bf(v.x * inv);
    o4.y = f2bf(v.y * inv);
    o4.z = f2bf(v.z * inv);
    o4.w = f2bf(v.w * inv);
    ((ushort4*)(qbf + (size_t)row * DDIM))[t] = o4;
}

// ---------- kernel 1b: keys f32 -> bf16 ----------
__global__ __launch_bounds__(256) void k_keys2bf(const float* __restrict__ keys,
                                                 unsigned short* __restrict__ kb) {
    int i = blockIdx.x * 256 + threadIdx.x;   // 4 floats per thread
    float4 v = ((const float4*)keys)[i];
    ushort4 o4;
    o4.x = f2bf(v.x);
    o4.y = f2bf(v.y);
    o4.z = f2bf(v.z);
    o4.w = f2bf(v.w);
    ((ushort4*)kb)[i] = o4;
}

// ---------- kernel 2: MFMA score GEMM + fused row-argmax / col-max ----------
// Tile: BM=128 (queries) x BN=128 (slots), BK=32. 4 waves in 2x2, each wave
// owns a 64x64 sub-tile = 4x4 fragments of 16x16. mfma_f32_16x16x32_bf16.
__global__ __launch_bounds__(256) void k_score(const unsigned short* __restrict__ qbf,
                                               const unsigned short* __restrict__ keysbf,
                                               u64* __restrict__ rowpack,
                                               u32* __restrict__ colmax) {
    __shared__ unsigned short sA[128 * 32];   // [row][k] 64 B rows
    __shared__ unsigned short sB[128 * 32];

    int t = threadIdx.x;
    int lane = t & 63;
    int wid = t >> 6;            // 0..3
    int wrow = wid >> 1;         // 0..1
    int wcol = wid & 1;          // 0..1
    int lr = lane & 15;          // frag row (A) / col (B)
    int kc = lane >> 4;          // k-chunk 0..3 (8 bf16 each)

    int n0 = blockIdx.y * 128;   // query block
    int j0 = blockIdx.x * 128;   // slot block

    // staging indices: thread t -> LDS bytes t*16, i.e. row t>>2, 16B-slot t&3
    int srow = t >> 2;
    int scol = (t & 3) * 8;      // bf16 elements

    f32x4 acc[4][4] = {};

    for (int k0 = 0; k0 < DDIM; k0 += 32) {
        __syncthreads();
        // A tile: 128 rows x 32 bf16 (two 64-row issues)
        gld_lds16(qbf + (size_t)(n0 + srow) * DDIM + k0 + scol,        sA + t * 8);
        gld_lds16(qbf + (size_t)(n0 + 64 + srow) * DDIM + k0 + scol,   sA + 2048 + t * 8);
        // B tile (keys rows = output cols)
        gld_lds16(keysbf + (size_t)(j0 + srow) * DDIM + k0 + scol,     sB + t * 8);
        gld_lds16(keysbf + (size_t)(j0 + 64 + srow) * DDIM + k0 + scol, sB + 2048 + t * 8);
        __syncthreads();

        bf16x8 a[4], b[4];
        #pragma unroll
        for (int i = 0; i < 4; ++i)
            a[i] = *(const bf16x8*)(sA + (wrow * 64 + i * 16 + lr) * 32 + kc * 8);
        #pragma unroll
        for (int j = 0; j < 4; ++j)
            b[j] = *(const bf16x8*)(sB + (wcol * 64 + j * 16 + lr) * 32 + kc * 8);
        #pragma unroll
        for (int i = 0; i < 4; ++i)
            #pragma unroll
            for (int j = 0; j < 4; ++j)
                acc[i][j] = __builtin_amdgcn_mfma_f32_16x16x32_bf16(a[i], b[j], acc[i][j], 0, 0, 0);
    }

    // ---- fused epilogue ----
    // C/D layout: col = lane&15 (=lr), row = (lane>>4)*4 + reg (=kc*4+r)
    // Row argmax over this wave's 64 cols:
    #pragma unroll
    for (int i = 0; i < 4; ++i) {
        #pragma unroll
        for (int r = 0; r < 4; ++r) {
            float v = acc[i][0][r];
            int c = j0 + wcol * 64 + lr;
            #pragma unroll
            for (int j = 1; j < 4; ++j) {
                float vj = acc[i][j][r];
                int cj = j0 + wcol * 64 + j * 16 + lr;
                if (vj > v) { v = vj; c = cj; }
            }
            #pragma unroll
            for (int off = 1; off < 16; off <<= 1) {
                float ov = __shfl_xor(v, off, 64);
                int oc = __shfl_xor(c, off, 64);
                if (ov > v || (ov == v && oc < c)) { v = ov; c = oc; }
            }
            if (lr == 0) {
                int grow = n0 + wrow * 64 + i * 16 + kc * 4 + r;
                u64 pk = ((u64)mapf(v) << 32) | (u64)(~(u32)c);  // ~col: ties -> lower col
                atomicMax(rowpack + grow, pk);
            }
        }
    }
    // Col max over this wave's 64 rows:
    #pragma unroll
    for (int j = 0; j < 4; ++j) {
        float m = acc[0][j][0];
        #pragma unroll
        for (int i = 0; i < 4; ++i)
            #pragma unroll
            for (int r = 0; r < 4; ++r) m = fmaxf(m, acc[i][j][r]);
        m = fmaxf(m, __shfl_xor(m, 16, 64));
        m = fmaxf(m, __shfl_xor(m, 32, 64));
        if (kc == 0) atomicMax(colmax + j0 + wcol * 64 + j * 16 + lr, mapf(m));
    }
}

// ---------- kernel 3: weights + scatter-add ----------
__global__ __launch_bounds__(128) void k_scatter(const unsigned short* __restrict__ qbf,
                                                 const u64* __restrict__ rowpack,
                                                 const u32* __restrict__ colmax,
                                                 float* __restrict__ upd) {
    int n = blockIdx.x;
    u64 p = rowpack[n];
    float val = unmapf((u32)(p >> 32));
    int g = (int)(~(u32)(p & 0xFFFFFFFFull));
    float cm = unmapf(colmax[g]);
    float w = expf(val - cm);
    int t = threadIdx.x;
    ushort4 u4 = ((const ushort4*)(qbf + (size_t)n * DDIM))[t];
    float* dst = upd + (size_t)g * DDIM + t * 4;
    atomicAdd(dst + 0, w * bf2f(u4.x));
    atomicAdd(dst + 1, w * bf2f(u4.y));
    atomicAdd(dst + 2, w * bf2f(u4.z));
    atomicAdd(dst + 3, w * bf2f(u4.w));
}

// ---------- kernel 4: final normalize ----------
__global__ __launch_bounds__(128) void k_final(const float* __restrict__ keys,
                                               const float* __restrict__ upd,
                                               float* __restrict__ out) {
    __shared__ float sred[2];
    int j = blockIdx.x;
    int t = threadIdx.x;
    float4 k4 = ((const float4*)(keys + (size_t)j * DDIM))[t];
    float4 u4 = ((const float4*)(upd + (size_t)j * DDIM))[t];
    float4 v;
    v.x = fmaf(TEMPU, u4.x, k4.x);
    v.y = fmaf(TEMPU, u4.y, k4.y);
    v.z = fmaf(TEMPU, u4.z, k4.z);
    v.w = fmaf(TEMPU, u4.w, k4.w);
    float ss = v.x * v.x + v.y * v.y + v.z * v.z + v.w * v.w;
    ss = block_reduce_sum_128(ss, sred, t);
    float inv = 1.0f / fmaxf(sqrtf(ss), EPSN);
    v.x *= inv; v.y *= inv; v.z *= inv; v.w *= inv;
    ((float4*)(out + (size_t)j * DDIM))[t] = v;
}

// ---------- launch ----------
extern "C" void kernel_launch(void* const* d_in, const int* in_sizes, int n_in,
                              void* d_out, int out_size, void* d_ws, size_t ws_size,
                              hipStream_t stream) {
    const float* query = (const float*)d_in[0];   // [16384, 512] f32
    const float* keys  = (const float*)d_in[1];   // [2048, 512] f32
    float* out = (float*)d_out;                   // [2048, 512] f32

    char* ws = (char*)d_ws;
    const size_t OFF_QBF  = 0;                    // 16384*512*2 = 16,777,216 B
    const size_t OFF_ROW  = 16777216;             // 16384*8     =    131,072 B
    const size_t OFF_CMAX = OFF_ROW + 131072;     // 2048*4      =      8,192 B
    const size_t OFF_UPD  = OFF_CMAX + 8192;      // 2048*512*4  =  4,194,304 B
    // keysbf ALIASES upd (keysbf dead after k_score; upd zeroed after it)

    unsigned short* qbf     = (unsigned short*)(ws + OFF_QBF);
    u64*            rowpack = (u64*)(ws + OFF_ROW);
    u32*            cmax    = (u32*)(ws + OFF_CMAX);
    float*          upd     = (float*)(ws + OFF_UPD);
    unsigned short* keysbf  = (unsigned short*)(ws + OFF_UPD);  // 2 MB, alias

    // zero rowpack + colmax (0 acts as -inf under mapf packing)
    hipMemsetAsync(ws + OFF_ROW, 0, 131072 + 8192, stream);

    k_normalize<<<N_Q, 128, 0, stream>>>(query, qbf);
    k_keys2bf<<<(M_SLOTS * DDIM / 4 + 255) / 256, 256, 0, stream>>>(keys, keysbf);

    dim3 g2(M_SLOTS / 128, N_Q / 128);  // 16 x 128
    k_score<<<g2, 256, 0, stream>>>(qbf, keysbf, rowpack, cmax);

    // now keysbf is dead; zero upd in its place
    hipMemsetAsync(ws + OFF_UPD, 0, (size_t)M_SLOTS * DDIM * 4, stream);

    k_scatter<<<N_Q, 128, 0, stream>>>(qbf, rowpack, cmax, upd);
    k_final<<<M_SLOTS, 128, 0, stream>>>(keys, upd, out);
}

// Round 3
// 106.485 us; speedup vs baseline: 5.3361x; 1.8811x over previous
//
#include <hip/hip_runtime.h>
#include <hip/hip_bf16.h>
#include <math.h>

#define N_Q     16384
#define DDIM    512
#define M_SLOTS 2048
#define EPSN    1e-12f
#define TEMPU   1e-5f

typedef unsigned int u32;
typedef unsigned long long u64;
typedef __attribute__((ext_vector_type(8))) short bf16x8;
typedef __attribute__((ext_vector_type(4))) float f32x4;

// ---------- helpers ----------
__device__ __forceinline__ u32 mapf(float f) {
    u32 b = __float_as_uint(f);
    return (b & 0x80000000u) ? ~b : (b | 0x80000000u);
}
__device__ __forceinline__ float unmapf(u32 u) {
    u32 b = (u & 0x80000000u) ? (u ^ 0x80000000u) : ~u;
    return __uint_as_float(b);
}
__device__ __forceinline__ float bf2f(unsigned short u) {
    return __uint_as_float(((u32)u) << 16);
}
__device__ __forceinline__ unsigned short f2bf(float f) {
    u32 b = __float_as_uint(f);
    u32 r = (b + 0x7FFFu + ((b >> 16) & 1u)) >> 16;  // RNE
    return (unsigned short)r;
}
__device__ __forceinline__ void gld_lds16(const unsigned short* g, unsigned short* l) {
    __builtin_amdgcn_global_load_lds(
        (const __attribute__((address_space(1))) u32*)(g),
        (__attribute__((address_space(3))) u32*)(l), 16, 0, 0);
}
__device__ __forceinline__ float block_reduce_sum_128(float v, float* sred, int t) {
    #pragma unroll
    for (int o = 32; o > 0; o >>= 1) v += __shfl_down(v, o, 64);
    if ((t & 63) == 0) sred[t >> 6] = v;
    __syncthreads();
    return sred[0] + sred[1];
}

// ---------- kernel 1: L2-normalize query rows, store bf16 ----------
__global__ __launch_bounds__(128) void k_normalize(const float* __restrict__ q,
                                                   unsigned short* __restrict__ qbf) {
    __shared__ float sred[2];
    int row = blockIdx.x;
    int t = threadIdx.x;
    const float* rp = q + (size_t)row * DDIM;
    float4 v = ((const float4*)rp)[t];
    float ss = v.x * v.x + v.y * v.y + v.z * v.z + v.w * v.w;
    ss = block_reduce_sum_128(ss, sred, t);
    float inv = 1.0f / fmaxf(sqrtf(ss), EPSN);
    ushort4 o4;
    o4.x = f2bf(v.x * inv);
    o4.y = f2bf(v.y * inv);
    o4.z = f2bf(v.z * inv);
    o4.w = f2bf(v.w * inv);
    ((ushort4*)(qbf + (size_t)row * DDIM))[t] = o4;
}

// ---------- kernel 1b: keys f32 -> bf16 ----------
__global__ __launch_bounds__(256) void k_keys2bf(const float* __restrict__ keys,
                                                 unsigned short* __restrict__ kb) {
    int i = blockIdx.x * 256 + threadIdx.x;   // 4 floats per thread
    float4 v = ((const float4*)keys)[i];
    ushort4 o4;
    o4.x = f2bf(v.x);
    o4.y = f2bf(v.y);
    o4.z = f2bf(v.z);
    o4.w = f2bf(v.w);
    ((ushort4*)kb)[i] = o4;
}

// ---------- kernel 2: MFMA score GEMM + fused row-argmax / col-max ----------
__global__ __launch_bounds__(256) void k_score(const unsigned short* __restrict__ qbf,
                                               const unsigned short* __restrict__ keysbf,
                                               u64* __restrict__ rowpack,
                                               u32* __restrict__ colmax) {
    __shared__ unsigned short sA[128 * 32];   // [row][k] 64 B rows
    __shared__ unsigned short sB[128 * 32];

    int t = threadIdx.x;
    int lane = t & 63;
    int wid = t >> 6;            // 0..3
    int wrow = wid >> 1;         // 0..1
    int wcol = wid & 1;          // 0..1
    int lr = lane & 15;          // frag row (A) / col (B)
    int kc = lane >> 4;          // k-chunk 0..3 (8 bf16 each)

    int n0 = blockIdx.y * 128;   // query block
    int j0 = blockIdx.x * 128;   // slot block

    int srow = t >> 2;
    int scol = (t & 3) * 8;      // bf16 elements

    f32x4 acc[4][4] = {};

    for (int k0 = 0; k0 < DDIM; k0 += 32) {
        __syncthreads();
        gld_lds16(qbf + (size_t)(n0 + srow) * DDIM + k0 + scol,         sA + t * 8);
        gld_lds16(qbf + (size_t)(n0 + 64 + srow) * DDIM + k0 + scol,    sA + 2048 + t * 8);
        gld_lds16(keysbf + (size_t)(j0 + srow) * DDIM + k0 + scol,      sB + t * 8);
        gld_lds16(keysbf + (size_t)(j0 + 64 + srow) * DDIM + k0 + scol, sB + 2048 + t * 8);
        __syncthreads();

        bf16x8 a[4], b[4];
        #pragma unroll
        for (int i = 0; i < 4; ++i)
            a[i] = *(const bf16x8*)(sA + (wrow * 64 + i * 16 + lr) * 32 + kc * 8);
        #pragma unroll
        for (int j = 0; j < 4; ++j)
            b[j] = *(const bf16x8*)(sB + (wcol * 64 + j * 16 + lr) * 32 + kc * 8);
        #pragma unroll
        for (int i = 0; i < 4; ++i)
            #pragma unroll
            for (int j = 0; j < 4; ++j)
                acc[i][j] = __builtin_amdgcn_mfma_f32_16x16x32_bf16(a[i], b[j], acc[i][j], 0, 0, 0);
    }

    // ---- fused epilogue ----
    // C/D layout: col = lane&15 (=lr), row = (lane>>4)*4 + reg (=kc*4+r)
    #pragma unroll
    for (int i = 0; i < 4; ++i) {
        #pragma unroll
        for (int r = 0; r < 4; ++r) {
            float v = acc[i][0][r];
            int c = j0 + wcol * 64 + lr;
            #pragma unroll
            for (int j = 1; j < 4; ++j) {
                float vj = acc[i][j][r];
                int cj = j0 + wcol * 64 + j * 16 + lr;
                if (vj > v) { v = vj; c = cj; }
            }
            #pragma unroll
            for (int off = 1; off < 16; off <<= 1) {
                float ov = __shfl_xor(v, off, 64);
                int oc = __shfl_xor(c, off, 64);
                if (ov > v || (ov == v && oc < c)) { v = ov; c = oc; }
            }
            if (lr == 0) {
                int grow = n0 + wrow * 64 + i * 16 + kc * 4 + r;
                u64 pk = ((u64)mapf(v) << 32) | (u64)(~(u32)c);  // ~col: ties -> lower col
                atomicMax(rowpack + grow, pk);
            }
        }
    }
    #pragma unroll
    for (int j = 0; j < 4; ++j) {
        float m = acc[0][j][0];
        #pragma unroll
        for (int i = 0; i < 4; ++i)
            #pragma unroll
            for (int r = 0; r < 4; ++r) m = fmaxf(m, acc[i][j][r]);
        m = fmaxf(m, __shfl_xor(m, 16, 64));
        m = fmaxf(m, __shfl_xor(m, 32, 64));
        if (kc == 0) atomicMax(colmax + j0 + wcol * 64 + j * 16 + lr, mapf(m));
    }
}

// ---------- kernel 3a: histogram of argmax slots ----------
__global__ __launch_bounds__(256) void k_hist(const u64* __restrict__ rowpack,
                                              u32* __restrict__ cnt) {
    int n = blockIdx.x * 256 + threadIdx.x;
    u64 p = rowpack[n];
    int g = (int)(~(u32)(p & 0xFFFFFFFFull));
    atomicAdd(cnt + g, 1u);
}

// ---------- kernel 3b: exclusive scan over 2048 counts (1 block) ----------
__global__ __launch_bounds__(256) void k_scan(const u32* __restrict__ cnt,
                                              u32* __restrict__ start,
                                              u32* __restrict__ cursor) {
    __shared__ u32 ssum[256];
    int t = threadIdx.x;
    u32 local[8], s = 0;
    #pragma unroll
    for (int i = 0; i < 8; ++i) { local[i] = cnt[t * 8 + i]; s += local[i]; }
    ssum[t] = s;
    __syncthreads();
    if (t == 0) {
        u32 a = 0;
        for (int i = 0; i < 256; ++i) { u32 v = ssum[i]; ssum[i] = a; a += v; }
    }
    __syncthreads();
    u32 run = ssum[t];
    #pragma unroll
    for (int i = 0; i < 8; ++i) {
        start[t * 8 + i] = run;
        cursor[t * 8 + i] = run;
        run += local[i];
    }
}

// ---------- kernel 3c: fill perm + weights ----------
__global__ __launch_bounds__(256) void k_fill(const u64* __restrict__ rowpack,
                                              const u32* __restrict__ colmax,
                                              u32* __restrict__ cursor,
                                              u32* __restrict__ perm,
                                              float* __restrict__ wval) {
    int n = blockIdx.x * 256 + threadIdx.x;
    u64 p = rowpack[n];
    float val = unmapf((u32)(p >> 32));
    int g = (int)(~(u32)(p & 0xFFFFFFFFull));
    float cm = unmapf(colmax[g]);
    float w = expf(val - cm);   // <= 1
    u32 pos = atomicAdd(cursor + g, 1u);
    perm[pos] = (u32)n;
    wval[pos] = w;
}

// ---------- kernel 4: gather + final normalize (fused) ----------
__global__ __launch_bounds__(128) void k_gather_final(const unsigned short* __restrict__ qbf,
                                                      const u32* __restrict__ start,
                                                      const u32* __restrict__ cnt,
                                                      const u32* __restrict__ perm,
                                                      const float* __restrict__ wval,
                                                      const float* __restrict__ keys,
                                                      float* __restrict__ out) {
    __shared__ float sred[2];
    int j = blockIdx.x;
    int t = threadIdx.x;
    u32 s = start[j];
    u32 e = s + cnt[j];
    float ax = 0.f, ay = 0.f, az = 0.f, aw = 0.f;
    for (u32 i = s; i < e; ++i) {
        u32 n = perm[i];
        float w = wval[i];
        ushort4 u4 = ((const ushort4*)(qbf + (size_t)n * DDIM))[t];
        ax = fmaf(w, bf2f(u4.x), ax);
        ay = fmaf(w, bf2f(u4.y), ay);
        az = fmaf(w, bf2f(u4.z), az);
        aw = fmaf(w, bf2f(u4.w), aw);
    }
    float4 k4 = ((const float4*)(keys + (size_t)j * DDIM))[t];
    float4 v;
    v.x = fmaf(TEMPU, ax, k4.x);
    v.y = fmaf(TEMPU, ay, k4.y);
    v.z = fmaf(TEMPU, az, k4.z);
    v.w = fmaf(TEMPU, aw, k4.w);
    float ss = v.x * v.x + v.y * v.y + v.z * v.z + v.w * v.w;
    ss = block_reduce_sum_128(ss, sred, t);
    float inv = 1.0f / fmaxf(sqrtf(ss), EPSN);
    v.x *= inv; v.y *= inv; v.z *= inv; v.w *= inv;
    ((float4*)(out + (size_t)j * DDIM))[t] = v;
}

// ---------- launch ----------
extern "C" void kernel_launch(void* const* d_in, const int* in_sizes, int n_in,
                              void* d_out, int out_size, void* d_ws, size_t ws_size,
                              hipStream_t stream) {
    const float* query = (const float*)d_in[0];   // [16384, 512] f32
    const float* keys  = (const float*)d_in[1];   // [2048, 512] f32
    float* out = (float*)d_out;                   // [2048, 512] f32

    char* ws = (char*)d_ws;
    const size_t OFF_QBF   = 0;                        // 16,777,216 B
    const size_t OFF_ROW   = 16777216;                 //    131,072 B  rowpack u64[16384]
    const size_t OFF_CMAX  = OFF_ROW + 131072;         //      8,192 B  colmax u32[2048]
    const size_t OFF_CNT   = OFF_CMAX + 8192;          //      8,192 B  cnt u32[2048]
    const size_t OFF_START = OFF_CNT + 8192;           //      8,192 B  start u32[2048]
    const size_t OFF_CUR   = OFF_START + 8192;         //      8,192 B  cursor u32[2048]
    const size_t OFF_PERM  = OFF_CUR + 8192;           //     65,536 B  perm u32[16384]
    const size_t OFF_W     = OFF_PERM + 65536;         //     65,536 B  wval f32[16384]
    const size_t OFF_KBF   = OFF_W + 65536;            //  2,097,152 B  keysbf

    unsigned short* qbf    = (unsigned short*)(ws + OFF_QBF);
    u64*            rowpack= (u64*)(ws + OFF_ROW);
    u32*            cmax   = (u32*)(ws + OFF_CMAX);
    u32*            cnt    = (u32*)(ws + OFF_CNT);
    u32*            start  = (u32*)(ws + OFF_START);
    u32*            cursor = (u32*)(ws + OFF_CUR);
    u32*            perm   = (u32*)(ws + OFF_PERM);
    float*          wval   = (float*)(ws + OFF_W);
    unsigned short* keysbf = (unsigned short*)(ws + OFF_KBF);

    // zero rowpack + colmax + cnt (0 acts as -inf under mapf packing)
    hipMemsetAsync(ws + OFF_ROW, 0, 131072 + 8192 + 8192, stream);

    k_normalize<<<N_Q, 128, 0, stream>>>(query, qbf);
    k_keys2bf<<<(M_SLOTS * DDIM / 4 + 255) / 256, 256, 0, stream>>>(keys, keysbf);

    dim3 g2(M_SLOTS / 128, N_Q / 128);  // 16 x 128
    k_score<<<g2, 256, 0, stream>>>(qbf, keysbf, rowpack, cmax);

    k_hist<<<N_Q / 256, 256, 0, stream>>>(rowpack, cnt);
    k_scan<<<1, 256, 0, stream>>>(cnt, start, cursor);
    k_fill<<<N_Q / 256, 256, 0, stream>>>(rowpack, cmax, cursor, perm, wval);
    k_gather_final<<<M_SLOTS, 128, 0, stream>>>(qbf, start, cnt, perm, wval, keys, out);
}